// Round 1
// baseline (1140.782 us; speedup 1.0000x reference)
//
#include <hip/hip_runtime.h>

typedef float  float4v __attribute__((ext_vector_type(4)));
typedef short  short8  __attribute__((ext_vector_type(8)));

__device__ __forceinline__ unsigned short f2bf(float f) {
    unsigned int u = __float_as_uint(f);
    u += 0x7fffu + ((u >> 16) & 1u);   // RNE
    return (unsigned short)(u >> 16);
}

// async global->LDS, 16B per lane; LDS dest must be the wave-uniform base
__device__ __forceinline__ void gload_lds16(const void* g, void* l) {
    __builtin_amdgcn_global_load_lds(
        (const __attribute__((address_space(1))) unsigned int*)g,
        (__attribute__((address_space(3))) unsigned int*)l, 16, 0, 0);
}

// ============================ FAST PATH (needs ~105 MB ws) ============================
// Workspace layout:
//   wt : bf16 weights, 589,824 B, blocked per (kblk,r,c0b): 1536 granules of 16B,
//        granule (s*128+kk)*4 + (q ^ ((kk>>1)&3)) holds c-chunk q (8 bf16) of (kk,s)
//   it : bf16 input, 104,595,456 B, [n][cc=4][h=112][pix=114] rows of 456 granules,
//        granule pix*4 + (q ^ ((pix>>1)&3)) holds c-chunk q of pixel w=pix-1,
//        pix==0 / pix==113 are zero (left/right pad baked in)
// Swizzle makes the conv kernel's ds_read_b128 fragment reads bank-balanced
// (2 lanes per 4-bank group) while keeping LDS writes LINEAR so global_load_lds works.

__global__ void wt_transform2(const float* __restrict__ w, unsigned short* __restrict__ wt) {
    int flat = blockIdx.x * 256 + threadIdx.x;     // 36,864 granules total
    int gq  = flat & 3;
    int g   = flat % 1536;
    int B   = flat / 1536;                          // (kblk*3 + r)*4 + c0b
    int row = g >> 2;                               // s*128 + kk
    int s   = row >> 7;
    int kk  = row & 127;
    int q   = gq ^ ((kk >> 1) & 3);
    int kblk = B / 12;
    int rc   = B % 12;
    int r    = rc >> 2;
    int c0b  = rc & 3;
    int k = kblk * 128 + kk;
    int c = c0b * 32 + q * 8;
    const float* src = w + ((size_t)(k * 128 + c)) * 9 + r * 3 + s;  // e-stride 9
    unsigned int v[4];
#pragma unroll
    for (int e = 0; e < 4; ++e)
        v[e] = (unsigned)f2bf(src[(2 * e) * 9]) | ((unsigned)f2bf(src[(2 * e + 1) * 9]) << 16);
    uint4 pk = make_uint4(v[0], v[1], v[2], v[3]);
    *(uint4*)&wt[(size_t)flat * 8] = pk;
}

__global__ void in_transform(const float* __restrict__ in, unsigned short* __restrict__ it) {
    int flat = blockIdx.x * 256 + threadIdx.x;      // 6,537,216 granules total
    int gq  = flat & 3;
    int p_  = flat >> 2;
    int pix = p_ % 114;
    int rest = p_ / 114;                            // nc*112 + h, nc = n*4+cc
    int h   = rest % 112;
    int nc  = rest / 112;
    uint4 pk = make_uint4(0u, 0u, 0u, 0u);
    if (pix >= 1 && pix <= 112) {
        int q = gq ^ ((pix >> 1) & 3);
        const float* src = in + ((size_t)(nc * 32 + q * 8) * 112 + h) * 112 + (pix - 1);
        unsigned int v[4];
#pragma unroll
        for (int e = 0; e < 4; ++e)
            v[e] = (unsigned)f2bf(src[(size_t)(2 * e) * 12544])
                 | ((unsigned)f2bf(src[(size_t)(2 * e + 1) * 12544]) << 16);
        pk = make_uint4(v[0], v[1], v[2], v[3]);
    }
    *(uint4*)&it[(size_t)flat * 8] = pk;
}

// main conv: M=128 outch (2 waves), N=2 rows x 112 w, K-loop = 4 c-chunks x 3 r x 3 s
__global__ __launch_bounds__(256, 3) void conv_mfma2(
    const unsigned short* __restrict__ it, const unsigned short* __restrict__ wt,
    const float* __restrict__ bias, float* __restrict__ out)
{
    __shared__ __align__(16) unsigned short s_in[4 * 114 * 32];  // 29,184 B, 1824 granules
    __shared__ __align__(16) unsigned short s_w [3 * 128 * 32];  // 24,576 B, 1536 granules

    const int tid    = threadIdx.x;
    const int lane   = tid & 63;
    const int wvb    = tid & 192;      // wave base (uniform within wave)
    const int wave_m = (tid >> 7) & 1; // which 64 outch
    const int p      = (tid >> 6) & 1; // which output row of the pair
    const int l15    = lane & 15;
    const int quad   = lane >> 4;
    const int aswz   = quad ^ ((l15 >> 1) & 3);   // weight-fragment swizzle (const per lane)

    const int kblk = blockIdx.x;       // 0..1 -> outch base kblk*128
    const int hb   = blockIdx.y * 2;   // output row pair base
    const int n    = blockIdx.z;

    float4v acc[4][7];
#pragma unroll
    for (int a = 0; a < 4; ++a)
#pragma unroll
        for (int t = 0; t < 7; ++t)
            acc[a][t] = (float4v){0.f, 0.f, 0.f, 0.f};

    const size_t nrow_base = (size_t)(n * 4) * 112;   // + c0b*112 + h  -> row index in it

    for (int c0b = 0; c0b < 4; ++c0b) {
        for (int r = 0; r < 3; ++r) {
            __syncthreads();   // protect s_w (and s_in on r==0) from previous compute

            // ---- stage weights for (kblk, r, c0b): 1536 granules, linear gld_lds ----
            {
                const unsigned short* wblk =
                    wt + ((size_t)((kblk * 3 + r) * 4 + c0b) * 1536) * 8;
#pragma unroll
                for (int i = 0; i < 6; ++i)
                    gload_lds16(wblk + (size_t)(i * 256 + tid) * 8,
                                &s_w[(i * 256 + wvb >> 0) * 8 + (size_t)0 + ( (tid & 192) - wvb) ]);
            }

            // ---- stage input (only once per c0b): 4 rows x 456 granules = 1824 ----
            if (r == 0) {
#pragma unroll
                for (int i = 0; i < 8; ++i) {
                    int flat = i * 256 + tid;
                    if (i < 7 || tid < 32) {       // 1824 granules
                        int hr = flat / 456;
                        int g  = flat - hr * 456;
                        int h_in = hb - 1 + hr;
                        if (h_in >= 0 && h_in < 112) {
                            const unsigned short* src =
                                it + (((nrow_base + (size_t)c0b * 112 + h_in) * 456) + g) * 8;
                            gload_lds16(src, &s_in[(i * 256 + wvb) * 8]);
                        } else {
                            *(uint4*)&s_in[(size_t)flat * 8] = make_uint4(0u, 0u, 0u, 0u);
                        }
                    }
                }
            }
            __syncthreads();   // (emits vmcnt(0) drain -> gld_lds complete)

            // ---- compute: 3 s x (4 A-frags + 7 x (1 B-frag + 4 MFMA)) ----
#pragma unroll
            for (int s = 0; s < 3; ++s) {
                short8 af[4];
#pragma unroll
                for (int a = 0; a < 4; ++a)
                    af[a] = *(const short8*)&s_w[(((s * 128 + wave_m * 64 + a * 16 + l15) << 2)
                                                  + aswz) * 8];
#pragma unroll
                for (int t = 0; t < 7; ++t) {
                    int pix  = t * 16 + l15 + s;
                    int bswz = quad ^ ((pix >> 1) & 3);
                    const short8 bf = *(const short8*)&s_in[((((p + r) * 114 + pix) << 2)
                                                             + bswz) * 8];
#pragma unroll
                    for (int a = 0; a < 4; ++a)
                        acc[a][t] = __builtin_amdgcn_mfma_f32_16x16x32_bf16(af[a], bf,
                                                                            acc[a][t], 0, 0, 0);
                }
            }
        }
    }

    // ---- epilogue: D col = lane&15 = w (coalesced), row = quad*4+reg = outch ----
    const int h_out = hb + p;
#pragma unroll
    for (int a = 0; a < 4; ++a) {
        int kk = kblk * 128 + wave_m * 64 + a * 16 + quad * 4;
        float b0 = bias[kk + 0], b1 = bias[kk + 1], b2 = bias[kk + 2], b3 = bias[kk + 3];
#pragma unroll
        for (int t = 0; t < 7; ++t) {
            int wcol = t * 16 + l15;
            size_t base = (((size_t)n * 256 + kk) * 112 + h_out) * 112 + wcol;
            out[base]             = acc[a][t][0] + b0;
            out[base + 12544]     = acc[a][t][1] + b1;
            out[base + 2 * 12544] = acc[a][t][2] + b2;
            out[base + 3 * 12544] = acc[a][t][3] + b3;
        }
    }
}

// ============================ FALLBACK PATH (previous kernel) ============================
__global__ void wt_transform(const float* __restrict__ w, unsigned short* __restrict__ wtb) {
    int idx = blockIdx.x * 256 + threadIdx.x;
    int c  = idx & 127;
    int t  = idx >> 7;
    int s  = t % 3;
    int kr = t / 3;
    int r  = kr % 3;
    int k  = kr / 3;
    wtb[idx] = f2bf(w[((size_t)(k * 128 + c)) * 9 + r * 3 + s]);
}

__global__ __launch_bounds__(256, 2) void conv_mfma(
    const float* __restrict__ in, const unsigned short* __restrict__ wtb,
    const float* __restrict__ bias, float* __restrict__ out)
{
    __shared__ __align__(16) unsigned short s_in[2 * 114 * 40];
    __shared__ __align__(16) unsigned short s_w [3 * 128 * 40];

    const int tid    = threadIdx.x;
    const int lane   = tid & 63;
    const int wv     = tid >> 6;
    const int wave_m = wv >> 1;
    const int p      = wv & 1;
    const int l15    = lane & 15;
    const int quad   = lane >> 4;

    const int k0    = blockIdx.x * 128;
    const int hb    = blockIdx.y * 2;
    const int n_idx = blockIdx.z;

    float4v acc[4][7];
#pragma unroll
    for (int a = 0; a < 4; ++a)
#pragma unroll
        for (int t = 0; t < 7; ++t)
            acc[a][t] = (float4v){0.f, 0.f, 0.f, 0.f};

    const float* in_n = in + (size_t)n_idx * 128 * 112 * 112;

    for (int r = 0; r < 3; ++r) {
        for (int c0 = 0; c0 < 128; c0 += 32) {
            __syncthreads();
#pragma unroll
            for (int i = 0; i < 8; ++i) {
                int flat = tid + i * 256;
                if (flat < 1824) {
                    int wi   = flat % 114;
                    int rest = flat / 114;
                    int row2 = rest & 1;
                    int cg   = rest >> 1;
                    int h_in = hb + row2 + r - 1;
                    int w    = wi - 1;
                    bool ok  = (h_in >= 0) && (h_in < 112) && (w >= 0) && (w < 112);
                    const float* src = in_n + ((size_t)(c0 + cg * 4) * 112 + (ok ? h_in : 0)) * 112
                                            + (ok ? w : 0);
                    float v0 = ok ? src[0]         : 0.f;
                    float v1 = ok ? src[12544]     : 0.f;
                    float v2 = ok ? src[2 * 12544] : 0.f;
                    float v3 = ok ? src[3 * 12544] : 0.f;
                    uint2 pk;
                    pk.x = (unsigned)f2bf(v0) | ((unsigned)f2bf(v1) << 16);
                    pk.y = (unsigned)f2bf(v2) | ((unsigned)f2bf(v3) << 16);
                    *(uint2*)&s_in[(row2 * 114 + wi) * 40 + cg * 4] = pk;
                }
            }
#pragma unroll
            for (int i = 0; i < 6; ++i) {
                int flat = tid + i * 256;
                int co8  = flat & 3;
                int s    = (flat >> 2) % 3;
                int kk   = flat / 12;
                const uint4 v = *(const uint4*)&wtb[((size_t)(k0 + kk) * 9 + r * 3 + s) * 128
                                                    + c0 + co8 * 8];
                *(uint4*)&s_w[(s * 128 + kk) * 40 + co8 * 8] = v;
            }
            __syncthreads();
#pragma unroll
            for (int s = 0; s < 3; ++s) {
                short8 af[4];
#pragma unroll
                for (int a = 0; a < 4; ++a)
                    af[a] = *(const short8*)&s_w[(s * 128 + wave_m * 64 + a * 16 + l15) * 40
                                                 + quad * 8];
#pragma unroll
                for (int t = 0; t < 7; ++t) {
                    short8 bf = *(const short8*)&s_in[(p * 114 + t * 16 + l15 + s) * 40 + quad * 8];
#pragma unroll
                    for (int a = 0; a < 4; ++a)
                        acc[a][t] = __builtin_amdgcn_mfma_f32_16x16x32_bf16(af[a], bf, acc[a][t],
                                                                            0, 0, 0);
                }
            }
        }
    }

    const int h_out = hb + p;
#pragma unroll
    for (int a = 0; a < 4; ++a) {
        int kk = k0 + wave_m * 64 + a * 16 + quad * 4;
        float b0 = bias[kk + 0], b1 = bias[kk + 1], b2 = bias[kk + 2], b3 = bias[kk + 3];
#pragma unroll
        for (int t = 0; t < 7; ++t) {
            int wcol = t * 16 + l15;
            size_t base = (((size_t)n_idx * 256 + kk) * 112 + h_out) * 112 + wcol;
            out[base]             = acc[a][t][0] + b0;
            out[base + 12544]     = acc[a][t][1] + b1;
            out[base + 2 * 12544] = acc[a][t][2] + b2;
            out[base + 3 * 12544] = acc[a][t][3] + b3;
        }
    }
}

__global__ void conv_naive(const float* __restrict__ in, const float* __restrict__ w,
                           const float* __restrict__ bias, float* __restrict__ out) {
    size_t idx = (size_t)blockIdx.x * 256 + threadIdx.x;
    if (idx >= (size_t)32 * 256 * 112 * 112) return;
    int wo = (int)(idx % 112);
    size_t t = idx / 112;
    int ho = (int)(t % 112); t /= 112;
    int k  = (int)(t % 256);
    int n  = (int)(t / 256);
    float acc = bias[k];
    for (int c = 0; c < 128; ++c)
        for (int r = 0; r < 3; ++r) {
            int hi = ho + r - 1;
            if (hi < 0 || hi >= 112) continue;
            for (int s = 0; s < 3; ++s) {
                int wi = wo + s - 1;
                if (wi < 0 || wi >= 112) continue;
                acc += in[((size_t)(n * 128 + c) * 112 + hi) * 112 + wi]
                     * w[((size_t)(k * 128 + c)) * 9 + r * 3 + s];
            }
        }
    out[idx] = acc;
}

extern "C" void kernel_launch(void* const* d_in, const int* in_sizes, int n_in,
                              void* d_out, int out_size, void* d_ws, size_t ws_size,
                              hipStream_t stream) {
    const float* in   = (const float*)d_in[0];
    const float* w    = (const float*)d_in[1];
    const float* bias = (const float*)d_in[2];
    float* out        = (float*)d_out;

    const size_t WT_BYTES = 589824;            // 36,864 granules * 16B
    const size_t IT_BYTES = 104595456ull;      // 6,537,216 granules * 16B

    if (ws_size >= WT_BYTES + IT_BYTES) {
        unsigned short* wt = (unsigned short*)d_ws;
        unsigned short* it = (unsigned short*)((char*)d_ws + WT_BYTES);
        wt_transform2<<<144, 256, 0, stream>>>(w, wt);
        in_transform<<<25536, 256, 0, stream>>>(in, it);
        conv_mfma2<<<dim3(2, 56, 32), dim3(256), 0, stream>>>(it, wt, bias, out);
    } else if (ws_size >= WT_BYTES) {
        unsigned short* wtb = (unsigned short*)d_ws;
        wt_transform<<<1152, 256, 0, stream>>>(w, wtb);
        conv_mfma<<<dim3(2, 56, 32), dim3(256), 0, stream>>>(in, wtb, bias, out);
    } else {
        size_t total = (size_t)32 * 256 * 112 * 112;
        conv_naive<<<(unsigned)((total + 255) / 256), 256, 0, stream>>>(in, w, bias, out);
    }
}

// Round 2
// 724.631 us; speedup vs baseline: 1.5743x; 1.5743x over previous
//
#include <hip/hip_runtime.h>

typedef float  float4v __attribute__((ext_vector_type(4)));
typedef short  short8  __attribute__((ext_vector_type(8)));

__device__ __forceinline__ unsigned short f2bf(float f) {
    unsigned int u = __float_as_uint(f);
    u += 0x7fffu + ((u >> 16) & 1u);   // RNE
    return (unsigned short)(u >> 16);
}

// async global->LDS, 16B per lane; LDS dest is wave-uniform base + lane*16
__device__ __forceinline__ void gload_lds16(const void* g, void* l) {
    __builtin_amdgcn_global_load_lds(
        (const __attribute__((address_space(1))) unsigned int*)g,
        (__attribute__((address_space(3))) unsigned int*)l, 16, 0, 0);
}

// ============================ FAST PATH (needs ~105 MB ws) ============================
// ws layout (identical to previous round — layouts verified passing):
//   wt : bf16 weights, 589,824 B, blocked per (kblk,r,c0b): 1536 granules of 16B,
//        granule (s*128+kk)*4 + (q ^ ((kk>>1)&3)) holds c-chunk q (8 bf16) of (kk,s)
//   it : bf16 input, 104,595,456 B, [n*4+cc][h=112] rows of 456 granules (7296 B),
//        granule pix*4 + (q ^ ((pix>>1)&3)) holds c-chunk q of pixel w=pix-1,
//        pix==0 / pix==113 are zero (left/right pad baked in)

__global__ void wt_transform2(const float* __restrict__ w, unsigned short* __restrict__ wt) {
    int flat = blockIdx.x * 256 + threadIdx.x;     // 36,864 granules total
    int gq  = flat & 3;
    int g   = flat % 1536;
    int B   = flat / 1536;                          // (kblk*3 + r)*4 + c0b
    int row = g >> 2;                               // s*128 + kk
    int s   = row >> 7;
    int kk  = row & 127;
    int q   = gq ^ ((kk >> 1) & 3);
    int kblk = B / 12;
    int rc   = B % 12;
    int r    = rc >> 2;
    int c0b  = rc & 3;
    int k = kblk * 128 + kk;
    int c = c0b * 32 + q * 8;
    const float* src = w + ((size_t)(k * 128 + c)) * 9 + r * 3 + s;  // elem stride 9
    unsigned int v[4];
#pragma unroll
    for (int e = 0; e < 4; ++e)
        v[e] = (unsigned)f2bf(src[(2 * e) * 9]) | ((unsigned)f2bf(src[(2 * e + 1) * 9]) << 16);
    *(uint4*)&wt[(size_t)flat * 8] = make_uint4(v[0], v[1], v[2], v[3]);
}

// coalesced transpose: one block per (nc, h) input row-slab (32 c x 112 w)
__global__ void in_transform(const float* __restrict__ in, unsigned short* __restrict__ it) {
    __shared__ __align__(16) unsigned short s_t[456 * 8];   // 7296 B
    const int b   = blockIdx.x;            // nc*112 + h, nc = n*4+cc
    const int h   = b % 112;
    const int nc  = b / 112;
    const int tid = threadIdx.x;

    if (tid < 8) {   // zero pad pixels: pix=0 -> granules 0..3, pix=113 -> 452..455
        int g = (tid < 4) ? tid : (448 + tid);
        *(uint4*)&s_t[g * 8] = make_uint4(0u, 0u, 0u, 0u);
    }
    const float* src_base = in + ((size_t)(nc * 32) * 112 + h) * 112;
    // 896 float4 slots: c = flat/28 (0..31), w4 = flat%28
#pragma unroll
    for (int i = 0; i < 4; ++i) {
        int flat = i * 256 + tid;
        if (flat < 896) {
            int c  = flat / 28;
            int w4 = flat - c * 28;
            float4 v = *(const float4*)(src_base + (size_t)c * 12544 + w4 * 4);
            int q = c >> 3, cl = c & 7;
            float vv[4] = {v.x, v.y, v.z, v.w};
#pragma unroll
            for (int e = 0; e < 4; ++e) {
                int pix = w4 * 4 + e + 1;
                int g   = pix * 4 + (q ^ ((pix >> 1) & 3));
                s_t[g * 8 + cl] = f2bf(vv[e]);
            }
        }
    }
    __syncthreads();
    unsigned short* dst = it + (size_t)b * 456 * 8;
#pragma unroll
    for (int i = 0; i < 2; ++i) {
        int g = i * 256 + tid;
        if (g < 456)
            *(uint4*)&dst[g * 8] = *(const uint4*)&s_t[g * 8];
    }
}

// main conv: M=128 outch (2 waves), N=2 rows x 112 w; 2-phase pipelined staging.
// LDS: s_w double-buffered (48 KB) + s_in 4-row ring (28.5 KB) = 78,336 B -> 2 blocks/CU
__global__ __launch_bounds__(256, 2) void conv_mfma2(
    const unsigned short* __restrict__ it, const unsigned short* __restrict__ wt,
    const float* __restrict__ bias, float* __restrict__ out)
{
    __shared__ __align__(16) unsigned short s_w [2][1536 * 8];  // 2 x 24,576 B
    __shared__ __align__(16) unsigned short s_in[4][456 * 8];   // 4 x  7,296 B

    const int tid    = threadIdx.x;
    const int lane   = tid & 63;
    const int wvb    = tid & 192;      // wave-uniform base
    const int wave_m = (tid >> 7) & 1; // which 64 outch
    const int p      = (tid >> 6) & 1; // which output row of the pair
    const int l15    = lane & 15;
    const int quad   = lane >> 4;
    const int aswz   = quad ^ ((l15 >> 1) & 3);

    const int kblk = blockIdx.x;       // 0..1
    const int k0   = kblk * 128;
    const int hb   = blockIdx.y * 2;
    const int n    = blockIdx.z;
    const int n4   = n * 4;

    float4v acc[4][7];
#pragma unroll
    for (int a = 0; a < 4; ++a)
#pragma unroll
        for (int t = 0; t < 7; ++t)
            acc[a][t] = (float4v){0.f, 0.f, 0.f, 0.f};

    // ---- staging helpers (inlined via lambdas) ----
    auto stage_w = [&](int c0b, int r, int buf) {
        const unsigned short* wblk = wt + ((size_t)((kblk * 3 + r) * 4 + c0b) * 1536) * 8;
#pragma unroll
        for (int i = 0; i < 6; ++i)
            gload_lds16(wblk + (size_t)(i * 256 + tid) * 8, &s_w[buf][(i * 256 + wvb) * 8]);
    };
    auto stage_in_row = [&](int c0b, int hr) {
        int h_in = hb - 1 + hr;
        if (h_in >= 0 && h_in < 112) {
            const unsigned short* src = it + (((size_t)(n4 + c0b) * 112 + h_in) * 456) * 8;
#pragma unroll
            for (int i = 0; i < 2; ++i) {
                int g = i * 256 + tid;
                if (g < 456)
                    gload_lds16(src + (size_t)g * 8, &s_in[hr][(i * 256 + wvb) * 8]);
            }
        } else {
#pragma unroll
            for (int i = 0; i < 2; ++i) {
                int g = i * 256 + tid;
                if (g < 456)
                    *(uint4*)&s_in[hr][g * 8] = make_uint4(0u, 0u, 0u, 0u);
            }
        }
    };

    // ---- prologue: weights for phase 0, input rows 0,1 of c-chunk 0 ----
    stage_w(0, 0, 0);
    stage_in_row(0, 0);
    stage_in_row(0, 1);
    __syncthreads();

    // ---- 12 phases, 1 barrier each; stage issued BEFORE compute (in flight during MFMA) ----
#pragma unroll
    for (int c0b = 0; c0b < 4; ++c0b) {
#pragma unroll
        for (int r = 0; r < 3; ++r) {
            const int ph  = c0b * 3 + r;
            const int cur = ph & 1;

            if (ph < 11) {               // prefetch next phase's weights into other buffer
                int nr = (r == 2) ? 0 : r + 1;
                int ncb = (r == 2) ? c0b + 1 : c0b;
                stage_w(ncb, nr, cur ^ 1);
            }
            // input ring: row slot dies exactly one phase before reuse
            if (r == 0)       stage_in_row(c0b, 2);
            else if (r == 1)  stage_in_row(c0b, 3);
            else if (c0b < 3) { stage_in_row(c0b + 1, 0); stage_in_row(c0b + 1, 1); }

            // compute on current buffers (reads rows p+r, p+r+1-range: slots r, r+1)
#pragma unroll
            for (int s = 0; s < 3; ++s) {
                short8 af[4];
#pragma unroll
                for (int a = 0; a < 4; ++a)
                    af[a] = *(const short8*)&s_w[cur][(((s * 128 + wave_m * 64 + a * 16 + l15) << 2)
                                                       + aswz) * 8];
#pragma unroll
                for (int t = 0; t < 7; ++t) {
                    int pix  = t * 16 + l15 + s;
                    int bswz = quad ^ ((pix >> 1) & 3);
                    const short8 bf = *(const short8*)&s_in[p + r][(pix * 4 + bswz) * 8];
#pragma unroll
                    for (int a = 0; a < 4; ++a)   // SWAPPED operands: D row=pixel, col=outch
                        acc[a][t] = __builtin_amdgcn_mfma_f32_16x16x32_bf16(bf, af[a],
                                                                            acc[a][t], 0, 0, 0);
                }
            }
            __syncthreads();   // drains staged loads; next phase's buffers ready
        }
    }

    // ---- epilogue: lane holds 4 consecutive pixels (quad*4+j) of channel a*16+l15 ----
    const int h_out = hb + p;
#pragma unroll
    for (int a = 0; a < 4; ++a) {
        int kk = k0 + wave_m * 64 + a * 16 + l15;
        float b = bias[kk];
        float* obase = out + (((size_t)(n * 256 + kk)) * 112 + h_out) * 112 + quad * 4;
#pragma unroll
        for (int t = 0; t < 7; ++t) {
            float4 v;
            v.x = acc[a][t][0] + b;
            v.y = acc[a][t][1] + b;
            v.z = acc[a][t][2] + b;
            v.w = acc[a][t][3] + b;
            *(float4*)(obase + t * 16) = v;
        }
    }
}

// ============================ FALLBACK PATHS ============================
__global__ void wt_transform(const float* __restrict__ w, unsigned short* __restrict__ wtb) {
    int idx = blockIdx.x * 256 + threadIdx.x;
    int c  = idx & 127;
    int t  = idx >> 7;
    int s  = t % 3;
    int kr = t / 3;
    int r  = kr % 3;
    int k  = kr / 3;
    wtb[idx] = f2bf(w[((size_t)(k * 128 + c)) * 9 + r * 3 + s]);
}

__global__ __launch_bounds__(256, 2) void conv_mfma(
    const float* __restrict__ in, const unsigned short* __restrict__ wtb,
    const float* __restrict__ bias, float* __restrict__ out)
{
    __shared__ __align__(16) unsigned short s_in[2 * 114 * 40];
    __shared__ __align__(16) unsigned short s_w [3 * 128 * 40];

    const int tid    = threadIdx.x;
    const int lane   = tid & 63;
    const int wv     = tid >> 6;
    const int wave_m = wv >> 1;
    const int p      = wv & 1;
    const int l15    = lane & 15;
    const int quad   = lane >> 4;

    const int k0    = blockIdx.x * 128;
    const int hb    = blockIdx.y * 2;
    const int n_idx = blockIdx.z;

    float4v acc[4][7];
#pragma unroll
    for (int a = 0; a < 4; ++a)
#pragma unroll
        for (int t = 0; t < 7; ++t)
            acc[a][t] = (float4v){0.f, 0.f, 0.f, 0.f};

    const float* in_n = in + (size_t)n_idx * 128 * 112 * 112;

    for (int r = 0; r < 3; ++r) {
        for (int c0 = 0; c0 < 128; c0 += 32) {
            __syncthreads();
#pragma unroll
            for (int i = 0; i < 8; ++i) {
                int flat = tid + i * 256;
                if (flat < 1824) {
                    int wi   = flat % 114;
                    int rest = flat / 114;
                    int row2 = rest & 1;
                    int cg   = rest >> 1;
                    int h_in = hb + row2 + r - 1;
                    int w    = wi - 1;
                    bool ok  = (h_in >= 0) && (h_in < 112) && (w >= 0) && (w < 112);
                    const float* src = in_n + ((size_t)(c0 + cg * 4) * 112 + (ok ? h_in : 0)) * 112
                                            + (ok ? w : 0);
                    float v0 = ok ? src[0]         : 0.f;
                    float v1 = ok ? src[12544]     : 0.f;
                    float v2 = ok ? src[2 * 12544] : 0.f;
                    float v3 = ok ? src[3 * 12544] : 0.f;
                    uint2 pk;
                    pk.x = (unsigned)f2bf(v0) | ((unsigned)f2bf(v1) << 16);
                    pk.y = (unsigned)f2bf(v2) | ((unsigned)f2bf(v3) << 16);
                    *(uint2*)&s_in[(row2 * 114 + wi) * 40 + cg * 4] = pk;
                }
            }
#pragma unroll
            for (int i = 0; i < 6; ++i) {
                int flat = tid + i * 256;
                int co8  = flat & 3;
                int s    = (flat >> 2) % 3;
                int kk   = flat / 12;
                const uint4 v = *(const uint4*)&wtb[((size_t)(k0 + kk) * 9 + r * 3 + s) * 128
                                                    + c0 + co8 * 8];
                *(uint4*)&s_w[(s * 128 + kk) * 40 + co8 * 8] = v;
            }
            __syncthreads();
#pragma unroll
            for (int s = 0; s < 3; ++s) {
                short8 af[4];
#pragma unroll
                for (int a = 0; a < 4; ++a)
                    af[a] = *(const short8*)&s_w[(s * 128 + wave_m * 64 + a * 16 + l15) * 40
                                                 + quad * 8];
#pragma unroll
                for (int t = 0; t < 7; ++t) {
                    short8 bf = *(const short8*)&s_in[(p * 114 + t * 16 + l15 + s) * 40 + quad * 8];
#pragma unroll
                    for (int a = 0; a < 4; ++a)
                        acc[a][t] = __builtin_amdgcn_mfma_f32_16x16x32_bf16(af[a], bf, acc[a][t],
                                                                            0, 0, 0);
                }
            }
        }
    }

    const int h_out = hb + p;
#pragma unroll
    for (int a = 0; a < 4; ++a) {
        int kk = k0 + wave_m * 64 + a * 16 + quad * 4;
        float b0 = bias[kk + 0], b1 = bias[kk + 1], b2 = bias[kk + 2], b3 = bias[kk + 3];
#pragma unroll
        for (int t = 0; t < 7; ++t) {
            int wcol = t * 16 + l15;
            size_t base = (((size_t)n_idx * 256 + kk) * 112 + h_out) * 112 + wcol;
            out[base]             = acc[a][t][0] + b0;
            out[base + 12544]     = acc[a][t][1] + b1;
            out[base + 2 * 12544] = acc[a][t][2] + b2;
            out[base + 3 * 12544] = acc[a][t][3] + b3;
        }
    }
}

__global__ void conv_naive(const float* __restrict__ in, const float* __restrict__ w,
                           const float* __restrict__ bias, float* __restrict__ out) {
    size_t idx = (size_t)blockIdx.x * 256 + threadIdx.x;
    if (idx >= (size_t)32 * 256 * 112 * 112) return;
    int wo = (int)(idx % 112);
    size_t t = idx / 112;
    int ho = (int)(t % 112); t /= 112;
    int k  = (int)(t % 256);
    int n  = (int)(t / 256);
    float acc = bias[k];
    for (int c = 0; c < 128; ++c)
        for (int r = 0; r < 3; ++r) {
            int hi = ho + r - 1;
            if (hi < 0 || hi >= 112) continue;
            for (int s = 0; s < 3; ++s) {
                int wi = wo + s - 1;
                if (wi < 0 || wi >= 112) continue;
                acc += in[((size_t)(n * 128 + c) * 112 + hi) * 112 + wi]
                     * w[((size_t)(k * 128 + c)) * 9 + r * 3 + s];
            }
        }
    out[idx] = acc;
}

extern "C" void kernel_launch(void* const* d_in, const int* in_sizes, int n_in,
                              void* d_out, int out_size, void* d_ws, size_t ws_size,
                              hipStream_t stream) {
    const float* in   = (const float*)d_in[0];
    const float* w    = (const float*)d_in[1];
    const float* bias = (const float*)d_in[2];
    float* out        = (float*)d_out;

    const size_t WT_BYTES = 589824;            // 36,864 granules * 16B
    const size_t IT_BYTES = 104595456ull;      // 6,537,216 granules * 16B

    if (ws_size >= WT_BYTES + IT_BYTES) {
        unsigned short* wt = (unsigned short*)d_ws;
        unsigned short* it = (unsigned short*)((char*)d_ws + WT_BYTES);
        wt_transform2<<<144, 256, 0, stream>>>(w, wt);
        in_transform<<<14336, 256, 0, stream>>>(in, it);
        conv_mfma2<<<dim3(2, 56, 32), dim3(256), 0, stream>>>(it, wt, bias, out);
    } else if (ws_size >= WT_BYTES) {
        unsigned short* wtb = (unsigned short*)d_ws;
        wt_transform<<<1152, 256, 0, stream>>>(w, wtb);
        conv_mfma<<<dim3(2, 56, 32), dim3(256), 0, stream>>>(in, wtb, bias, out);
    } else {
        size_t total = (size_t)32 * 256 * 112 * 112;
        conv_naive<<<(unsigned)((total + 255) / 256), 256, 0, stream>>>(in, w, bias, out);
    }
}